// Round 2
// baseline (5971.292 us; speedup 1.0000x reference)
//
#include <hip/hip_runtime.h>
#include <math.h>

#define U_N 10000
#define P_N 50000
#define T_N 48
#define W_N 10
#define S_N 4
#define DW_N 400
#define MW_N 12
#define E_N 1000000
#define SMALLROWS 74      // 48 time + 4 season + 10 weather + 12 month
#define XR 10112          // 79*128 padded rows for knn
#define NCH 8             // column chunks for knn grid
#define CT 79             // 10112/128 col tiles
#define EPSF 1e-9f

// ---- workspace offsets (in floats) ----
#define OFF_ACC_USER  0
#define OFF_ACC_POI   1280000
#define OFF_ACC_SMALL 7680000
#define OFF_DAYACC    7689472
#define OFF_CNT_USER  7740672
#define OFF_CNT_POI   7750672
#define OFF_CNT_SMALL 7800672
#define OFF_CNT_DAY   7800746
#define OFF_CU        7801152   // int[10000*400], 16B aligned
#define OFF_CP        11801152  // int[50000*400], 16B aligned
#define ZERO_END      31801152  // everything before here memset to 0
#define OFF_X         31801152
#define OFF_SQ        33095488
#define OFF_LISTS     33105600  // u64 region, 8B aligned

// ---- output offsets (floats) : user, poi, time, weather, season, day, month ----
#define O_USER 0
#define O_POI  1280000
#define O_TIME 7680000
#define O_WEA  7686144
#define O_SEA  7687424
#define O_DAY  7687936
#define O_MON  7739136

__device__ inline void at4(float* p, float a, float b, float c, float d) {
    unsafeAtomicAdd(p + 0, a);
    unsafeAtomicAdd(p + 1, b);
    unsafeAtomicAdd(p + 2, c);
    unsafeAtomicAdd(p + 3, d);
}

__device__ inline void lds_at4(float* p, float a, float b, float c, float d) {
    atomicAdd(p + 0, a);
    atomicAdd(p + 1, b);
    atomicAdd(p + 2, c);
    atomicAdd(p + 3, d);
}

// ============================================================================
// K2: one streaming pass over edges. Reads e_W (512MB, HBM floor ~81us),
// gathers u/p/t rows (cache-resident), scatters:
//   msg_user = p+t+w -> acc_user[u]   (128 f32 global atomics / edge)
//   msg_poi  = u+t+w -> acc_poi[p]    (128 f32 global atomics / edge)
//   msg_up   = u+p   -> time/season/weather/month (LDS privatized f32)
//   day: ONLY count histograms Cu[u][d]++ / Cp[p][d]++ (6 int atomics / edge)
// ============================================================================
__global__ __launch_bounds__(256) void k_edge(
    const float4* __restrict__ uemb, const float4* __restrict__ pemb,
    const float4* __restrict__ temb, const float4* __restrict__ ew,
    const int* __restrict__ u_idx, const int* __restrict__ p_idx,
    const int* __restrict__ t_idx, const int* __restrict__ s_idx,
    const int* __restrict__ wn_idx, const int* __restrict__ wd_idx,
    const int* __restrict__ wm_idx,
    float* __restrict__ acc_user, float* __restrict__ acc_poi,
    float* __restrict__ acc_small,
    int* __restrict__ Cu, int* __restrict__ Cp,
    float* __restrict__ cnt_user, float* __restrict__ cnt_poi,
    float* __restrict__ cnt_small, float* __restrict__ cnt_day)
{
    __shared__ float ls[SMALLROWS * 128];
    __shared__ float lc[SMALLROWS + DW_N];
    for (int i = threadIdx.x; i < SMALLROWS * 128; i += 256) ls[i] = 0.f;
    for (int i = threadIdx.x; i < SMALLROWS + DW_N; i += 256) lc[i] = 0.f;
    __syncthreads();

    int per = (E_N + gridDim.x - 1) / gridDim.x;
    int e0 = blockIdx.x * per;
    int e1 = min(E_N, e0 + per);
    int wv = threadIdx.x >> 6;
    int ln = threadIdx.x & 63;
    int sub = ln >> 5, c4 = ln & 31;
    int cb = c4 * 4;

    for (int e = e0 + wv * 2 + sub; e < e1; e += 8) {
        int u = u_idx[e], p = p_idx[e], t = t_idx[e];
        int s = s_idx[e], wn = wn_idx[e], wm = wm_idx[e];
        float4 uf = uemb[u * 32 + c4];
        float4 pf = pemb[p * 32 + c4];
        float4 tf = temb[t * 32 + c4];
        float4 wf = ew[(size_t)e * 32 + c4];

        // user message: p + t + w
        at4(acc_user + u * 128 + cb,
            pf.x + tf.x + wf.x, pf.y + tf.y + wf.y,
            pf.z + tf.z + wf.z, pf.w + tf.w + wf.w);
        // poi message: u + t + w
        at4(acc_poi + p * 128 + cb,
            uf.x + tf.x + wf.x, uf.y + tf.y + wf.y,
            uf.z + tf.z + wf.z, uf.w + tf.w + wf.w);
        // shared message: u + p -> LDS-privatized small targets
        float mx = uf.x + pf.x, my = uf.y + pf.y, mz = uf.z + pf.z, mw = uf.w + pf.w;
        lds_at4(ls + t * 128 + cb, mx, my, mz, mw);
        lds_at4(ls + (T_N + s) * 128 + cb, mx, my, mz, mw);
        lds_at4(ls + (52 + wn) * 128 + cb, mx, my, mz, mw);
        lds_at4(ls + (62 + wm) * 128 + cb, mx, my, mz, mw);

        if (c4 == 0) {
            int w0 = wd_idx[e * 3 + 0], w1 = wd_idx[e * 3 + 1], w2 = wd_idx[e * 3 + 2];
            atomicAdd(&lc[t], 1.f);
            atomicAdd(&lc[T_N + s], 1.f);
            atomicAdd(&lc[52 + wn], 1.f);
            atomicAdd(&lc[62 + wm], 1.f);
            atomicAdd(&lc[SMALLROWS + w0], 1.f);
            atomicAdd(&lc[SMALLROWS + w1], 1.f);
            atomicAdd(&lc[SMALLROWS + w2], 1.f);
            atomicAdd(&Cu[u * DW_N + w0], 1);
            atomicAdd(&Cu[u * DW_N + w1], 1);
            atomicAdd(&Cu[u * DW_N + w2], 1);
            atomicAdd(&Cp[p * DW_N + w0], 1);
            atomicAdd(&Cp[p * DW_N + w1], 1);
            atomicAdd(&Cp[p * DW_N + w2], 1);
            unsafeAtomicAdd(cnt_user + u, 1.f);
            unsafeAtomicAdd(cnt_poi + p, 1.f);
        }
    }
    __syncthreads();
    for (int i = threadIdx.x; i < SMALLROWS * 128; i += 256)
        if (ls[i] != 0.f) unsafeAtomicAdd(&acc_small[i], ls[i]);
    for (int i = threadIdx.x; i < SMALLROWS; i += 256)
        if (lc[i] != 0.f) unsafeAtomicAdd(&cnt_small[i], lc[i]);
    for (int i = threadIdx.x; i < DW_N; i += 256)
        if (lc[SMALLROWS + i] != 0.f) unsafeAtomicAdd(&cnt_day[i], lc[SMALLROWS + i]);
}

// ============================================================================
// K2b: count-matrix GEMM  day_acc[d][n] += sum_k C[k][d] * emb[k][n]
// grid = (13 dtiles of 32 days, kstrips). Thread: 8 days x 2 cols micro-tile.
// ============================================================================
#define DTILE 32
#define KB 16

__global__ __launch_bounds__(256) void k_cgemm(
    const float* __restrict__ emb, const int* __restrict__ C,
    int K, int kper, float* __restrict__ day_acc)
{
    __shared__ __align__(16) float se[KB][128];
    __shared__ __align__(16) int   sc[KB][DTILE];
    int d0 = blockIdx.x * DTILE;
    int k0 = blockIdx.y * kper;
    int k1 = min(K, k0 + kper);
    int n2 = (threadIdx.x & 63) * 2;
    int dg = threadIdx.x >> 6;      // 0..3
    int dbase = dg * 8;

    float acc[8][2];
#pragma unroll
    for (int j = 0; j < 8; j++) { acc[j][0] = 0.f; acc[j][1] = 0.f; }

    for (int kb = k0; kb < k1; kb += KB) {
        int kn = min(KB, k1 - kb);
        __syncthreads();
        for (int t = threadIdx.x; t < KB * 64; t += 256) {
            int kk = t >> 6, cc = (t & 63) * 2;
            float2 v;
            if (kb + kk < k1) v = *(const float2*)&emb[(size_t)(kb + kk) * 128 + cc];
            else { v.x = 0.f; v.y = 0.f; }
            *(float2*)&se[kk][cc] = v;
        }
        for (int t = threadIdx.x; t < KB * DTILE; t += 256) {
            int kk = t >> 5, dd = t & 31;
            int d = d0 + dd;
            sc[kk][dd] = (kb + kk < k1 && d < DW_N) ? C[(size_t)(kb + kk) * DW_N + d] : 0;
        }
        __syncthreads();
        for (int kk = 0; kk < kn; kk++) {
            float2 e = *(const float2*)&se[kk][n2];
            int4 c0 = *(const int4*)&sc[kk][dbase];
            int4 c1 = *(const int4*)&sc[kk][dbase + 4];
            float cf[8] = { (float)c0.x, (float)c0.y, (float)c0.z, (float)c0.w,
                            (float)c1.x, (float)c1.y, (float)c1.z, (float)c1.w };
#pragma unroll
            for (int j = 0; j < 8; j++) {
                acc[j][0] = fmaf(cf[j], e.x, acc[j][0]);
                acc[j][1] = fmaf(cf[j], e.y, acc[j][1]);
            }
        }
    }
#pragma unroll
    for (int j = 0; j < 8; j++) {
        int d = d0 + dbase + j;
        if (d < DW_N) {
            unsafeAtomicAdd(&day_acc[d * 128 + n2], acc[j][0]);
            unsafeAtomicAdd(&day_acc[d * 128 + n2 + 1], acc[j][1]);
        }
    }
}

// ============================================================================
// K3a: day mean
// ============================================================================
__global__ __launch_bounds__(256) void k_day(
    const float* __restrict__ day_acc, const float* __restrict__ cnt_day,
    float* __restrict__ outday)
{
    int idx = blockIdx.x * 256 + threadIdx.x;   // < 51200
    int d = idx >> 7;
    outday[idx] = day_acc[idx] / (cnt_day[d] + EPSF);
}

// ============================================================================
// K3b: normalize user accumulator -> X (padded), compute per-row sumsq
// ============================================================================
__global__ __launch_bounds__(256) void k_norm_user(
    const float* __restrict__ acc_user, const float* __restrict__ cnt_user,
    float* __restrict__ X, float* __restrict__ sq)
{
    int half = threadIdx.x >> 7;
    int c = threadIdx.x & 127;
    int row = blockIdx.x * 2 + half;
    float v = 0.f;
    if (row < U_N) v = acc_user[row * 128 + c] / (cnt_user[row] + EPSF);
    X[row * 128 + c] = v;
    __shared__ float red[256];
    red[threadIdx.x] = v * v;
    __syncthreads();
    for (int s = 64; s > 0; s >>= 1) {
        if ((threadIdx.x & 127) < s) red[threadIdx.x] += red[threadIdx.x + s];
        __syncthreads();
    }
    if (c == 0) sq[row] = (row < U_N) ? red[threadIdx.x] : INFINITY;
}

// ============================================================================
// K3c: normalize poi -> out
// ============================================================================
__global__ __launch_bounds__(256) void k_norm_poi(
    const float* __restrict__ acc_poi, const float* __restrict__ cnt_poi,
    float* __restrict__ outpoi)
{
    for (int idx = blockIdx.x * 256 + threadIdx.x; idx < P_N * 128;
         idx += gridDim.x * 256) {
        int p = idx >> 7;
        outpoi[idx] = acc_poi[idx] / (cnt_poi[p] + EPSF);
    }
}

// ============================================================================
// K3d: normalize small targets -> out (time / season / weather / month)
// ============================================================================
__global__ __launch_bounds__(256) void k_norm_small(
    const float* __restrict__ accs, const float* __restrict__ cnts,
    float* __restrict__ out)
{
    int idx = blockIdx.x * 256 + threadIdx.x;
    if (idx >= SMALLROWS * 128) return;
    int row = idx >> 7, c = idx & 127;
    float v = accs[idx] / (cnts[row] + EPSF);
    int off;
    if (row < 48)      off = O_TIME + row * 128 + c;
    else if (row < 52) off = O_SEA + (row - 48) * 128 + c;
    else if (row < 62) off = O_WEA + (row - 52) * 128 + c;
    else               off = O_MON + (row - 62) * 128 + c;
    out[off] = v;
}

// ============================================================================
// K5: knn — f32 tiled GEMM (X @ X^T) with fused online top-6 per row.
// (d2,idx) packed in u64 => single compare reproduces top_k tie-breaking.
// ============================================================================
#define KNN_PAD 134

__device__ inline void ins6(unsigned long long (&l)[6], unsigned long long cand) {
    if (cand < l[5]) {
        l[5] = cand;
#pragma unroll
        for (int k = 5; k >= 1; k--) {
            unsigned long long a = l[k - 1], b = l[k];
            l[k - 1] = (b < a) ? b : a;
            l[k] = (b < a) ? a : b;
        }
    }
}

__global__ __launch_bounds__(256) void k_knn(
    const float* __restrict__ X, const float* __restrict__ sq,
    unsigned long long* __restrict__ lists)
{
    __shared__ __align__(16) unsigned char smem[49152];
    float* Ab = (float*)smem;                  // [32][KNN_PAD]
    float* Bb = Ab + 32 * KNN_PAD;
    unsigned long long* mb = (unsigned long long*)smem;  // [128][8][6] reuse

    int rb = blockIdx.x / NCH, ch = blockIdx.x % NCH;
    int row0 = rb * 128;
    int tid = threadIdx.x;
    int tr = tid >> 3;   // 0..31 -> rows tr*4 .. +3
    int tc = tid & 7;    // 0..7  -> cols tc*16 .. +15

    float sqr[4];
#pragma unroll
    for (int i = 0; i < 4; i++) sqr[i] = sq[row0 + tr * 4 + i];

    unsigned long long lst[4][6];
#pragma unroll
    for (int i = 0; i < 4; i++)
#pragma unroll
        for (int k = 0; k < 6; k++) lst[i][k] = ~0ull;

    for (int ct = ch; ct < CT; ct += NCH) {
        int col0 = ct * 128;
        float acc[4][16];
#pragma unroll
        for (int i = 0; i < 4; i++)
#pragma unroll
            for (int j = 0; j < 16; j++) acc[i][j] = 0.f;

        for (int kc = 0; kc < 4; kc++) {
            __syncthreads();
#pragma unroll
            for (int i = 0; i < 16; i++) {
                int lin = i * 256 + tid;
                int r = lin >> 5, kk = lin & 31;
                Ab[kk * KNN_PAD + r] = X[(row0 + r) * 128 + kc * 32 + kk];
                Bb[kk * KNN_PAD + r] = X[(col0 + r) * 128 + kc * 32 + kk];
            }
            __syncthreads();
#pragma unroll 2
            for (int kk = 0; kk < 32; kk++) {
                float a[4], b[16];
                float2 t0 = *(const float2*)&Ab[kk * KNN_PAD + tr * 4];
                float2 t1 = *(const float2*)&Ab[kk * KNN_PAD + tr * 4 + 2];
                a[0] = t0.x; a[1] = t0.y; a[2] = t1.x; a[3] = t1.y;
#pragma unroll
                for (int j = 0; j < 8; j++) {
                    float2 tb = *(const float2*)&Bb[kk * KNN_PAD + tc * 16 + j * 2];
                    b[2 * j] = tb.x; b[2 * j + 1] = tb.y;
                }
#pragma unroll
                for (int i = 0; i < 4; i++)
#pragma unroll
                    for (int j = 0; j < 16; j++)
                        acc[i][j] = fmaf(a[i], b[j], acc[i][j]);
            }
        }
#pragma unroll
        for (int j = 0; j < 16; j++) {
            int col = col0 + tc * 16 + j;
            float sqc = sq[col];
#pragma unroll
            for (int i = 0; i < 4; i++) {
                float d2 = fmaxf(fmaf(-2.f, acc[i][j], sqr[i] + sqc), 0.f);
                unsigned long long cand =
                    ((unsigned long long)__float_as_uint(d2) << 32) | (unsigned)col;
                ins6(lst[i], cand);
            }
        }
    }
    __syncthreads();
#pragma unroll
    for (int i = 0; i < 4; i++)
#pragma unroll
        for (int k = 0; k < 6; k++)
            mb[((tr * 4 + i) * 8 + tc) * 6 + k] = lst[i][k];
    __syncthreads();
    if (tid < 128) {
        unsigned long long outl[6];
#pragma unroll
        for (int k = 0; k < 6; k++) outl[k] = ~0ull;
        for (int t = 0; t < 8; t++)
            for (int k = 0; k < 6; k++)
                ins6(outl, mb[(tid * 8 + t) * 6 + k]);
#pragma unroll
        for (int k = 0; k < 6; k++)
            lists[((size_t)(row0 + tid) * NCH + ch) * 6 + k] = outl[k];
    }
}

// ============================================================================
// K6: merge per-chunk top-6 lists, gather 6 rows of X, mean -> out user region
// ============================================================================
__global__ __launch_bounds__(256) void k_final(
    const unsigned long long* __restrict__ lists,
    const float* __restrict__ X, float* __restrict__ out)
{
    int row = blockIdx.x * 4 + (threadIdx.x >> 6);
    int ln = threadIdx.x & 63;
    unsigned long long l[6];
#pragma unroll
    for (int k = 0; k < 6; k++) l[k] = ~0ull;
    if (ln == 0) {
        for (int t = 0; t < NCH; t++)
            for (int k = 0; k < 6; k++)
                ins6(l, lists[((size_t)row * NCH + t) * 6 + k]);
    }
    float s0 = 0.f, s1 = 0.f;
#pragma unroll
    for (int k = 0; k < 6; k++) {
        int idx = __shfl((int)(unsigned)l[k], 0);
        s0 += X[idx * 128 + ln];
        s1 += X[idx * 128 + 64 + ln];
    }
    out[row * 128 + ln] = s0 * (1.f / 6.f);
    out[row * 128 + 64 + ln] = s1 * (1.f / 6.f);
}

// ============================================================================
extern "C" void kernel_launch(void* const* d_in, const int* in_sizes, int n_in,
                              void* d_out, int out_size, void* d_ws, size_t ws_size,
                              hipStream_t stream) {
    const float4* uemb = (const float4*)d_in[0];
    const float4* pemb = (const float4*)d_in[1];
    const float4* temb = (const float4*)d_in[2];
    // d_in[3..6]: weather/season/day/month embeddings — unused by reference math
    const float4* ew = (const float4*)d_in[7];
    const int* u_idx = (const int*)d_in[8];
    const int* p_idx = (const int*)d_in[9];
    const int* t_idx = (const int*)d_in[10];
    const int* s_idx = (const int*)d_in[11];
    const int* wn_idx = (const int*)d_in[12];
    const int* wd_idx = (const int*)d_in[13];
    const int* wm_idx = (const int*)d_in[14];

    float* out = (float*)d_out;
    float* ws = (float*)d_ws;

    float* acc_user = ws + OFF_ACC_USER;
    float* acc_poi = ws + OFF_ACC_POI;
    float* acc_small = ws + OFF_ACC_SMALL;
    float* day_acc = ws + OFF_DAYACC;
    float* cnt_user = ws + OFF_CNT_USER;
    float* cnt_poi = ws + OFF_CNT_POI;
    float* cnt_small = ws + OFF_CNT_SMALL;
    float* cnt_day = ws + OFF_CNT_DAY;
    int* Cu = (int*)(ws + OFF_CU);
    int* Cp = (int*)(ws + OFF_CP);
    float* X = ws + OFF_X;
    float* sqv = ws + OFF_SQ;
    unsigned long long* lists = (unsigned long long*)(ws + OFF_LISTS);

    hipMemsetAsync(d_ws, 0, (size_t)ZERO_END * sizeof(float), stream);

    k_edge<<<1024, 256, 0, stream>>>(uemb, pemb, temb, ew,
                                     u_idx, p_idx, t_idx, s_idx, wn_idx, wd_idx, wm_idx,
                                     acc_user, acc_poi, acc_small, Cu, Cp,
                                     cnt_user, cnt_poi, cnt_small, cnt_day);

    // day = Cu^T @ user_emb + Cp^T @ poi_emb
    k_cgemm<<<dim3(13, 8), 256, 0, stream>>>((const float*)uemb, Cu, U_N, 1250, day_acc);
    k_cgemm<<<dim3(13, 40), 256, 0, stream>>>((const float*)pemb, Cp, P_N, 1250, day_acc);

    k_day<<<DW_N * 128 / 256, 256, 0, stream>>>(day_acc, cnt_day, out + O_DAY);
    k_norm_user<<<XR / 2, 256, 0, stream>>>(acc_user, cnt_user, X, sqv);
    k_norm_poi<<<2048, 256, 0, stream>>>(acc_poi, cnt_poi, out + O_POI);
    k_norm_small<<<(SMALLROWS * 128 + 255) / 256, 256, 0, stream>>>(acc_small, cnt_small, out);

    k_knn<<<CT * NCH, 256, 0, stream>>>(X, sqv, lists);
    k_final<<<U_N / 4, 256, 0, stream>>>(lists, X, out + O_USER);
}

// Round 3
// 2852.123 us; speedup vs baseline: 2.0936x; 2.0936x over previous
//
#include <hip/hip_runtime.h>
#include <math.h>

#define U_N 10000
#define P_N 50000
#define T_N 48
#define W_N 10
#define S_N 4
#define DW_N 400
#define MW_N 12
#define E_N 1000000
#define XR 10112          // 79*128 padded rows for knn
#define NCH 8             // column chunks for knn grid
#define CT 79             // 10112/128 col tiles
#define EPSF 1e-9f
#define NCOL 474          // 48 time + 4 season + 10 weather + 12 month + 400 day
#define CSTR 480          // padded row stride of count matrices

// ---- workspace offsets (in floats) ----
#define OFF_CNT_U   0
#define OFF_CNT_P   10000
#define OFF_OFF_U   60000        // int[10001]
#define OFF_OFF_P   70016        // int[50001]
#define OFF_CUR_U   120032
#define OFF_CUR_P   130032
#define OFF_UPACK   180032       // int4[1M]   (k_knn lists overlay here later)
#define OFF_PPACK   4180032      // int4[1M]
#define OFF_CU      8180032      // u8[10000*480]
#define OFF_CP      9380032      // u8[50000*480]
#define OFF_ACC474  15380032     // float[480*128]
#define OFF_CNTALL  15441472     // float[480]
#define OFF_X       15441952     // float[10112*128]
#define OFF_SQ      16736288     // float[10112]
// total 16,746,400 floats ~= 67 MB

// ---- output offsets (floats): user, poi, time, weather, season, day, month ----
#define O_USER 0
#define O_POI  1280000
#define O_TIME 7680000
#define O_WEA  7686144
#define O_SEA  7687424
#define O_DAY  7687936
#define O_MON  7739136

// ============================================================================
// K0: degree histograms (int atomics into L2-resident 240KB)
// ============================================================================
__global__ __launch_bounds__(256) void k_hist(
    const int* __restrict__ u_idx, const int* __restrict__ p_idx,
    int* __restrict__ cnt_u, int* __restrict__ cnt_p)
{
    for (int e = blockIdx.x * 256 + threadIdx.x; e < E_N; e += gridDim.x * 256) {
        atomicAdd(&cnt_u[u_idx[e]], 1);
        atomicAdd(&cnt_p[p_idx[e]], 1);
    }
}

// ============================================================================
// K1: exclusive scan (block 0: users, block 1: pois) -> off[n+1], cur copy
// ============================================================================
__global__ __launch_bounds__(1024) void k_scan(
    const int* __restrict__ cnt_u, int* __restrict__ off_u, int* __restrict__ cur_u,
    const int* __restrict__ cnt_p, int* __restrict__ off_p, int* __restrict__ cur_p)
{
    const int n = (blockIdx.x == 0) ? U_N : P_N;
    const int* cnt = (blockIdx.x == 0) ? cnt_u : cnt_p;
    int* off = (blockIdx.x == 0) ? off_u : off_p;
    int* cur = (blockIdx.x == 0) ? cur_u : cur_p;
    __shared__ int sd[1024];
    int per = (n + 1023) >> 10;
    int base = threadIdx.x * per;
    int s = 0;
    for (int j = 0; j < per; j++) {
        int idx = base + j;
        if (idx < n) s += cnt[idx];
    }
    sd[threadIdx.x] = s;
    __syncthreads();
    for (int d = 1; d < 1024; d <<= 1) {
        int t = (threadIdx.x >= d) ? sd[threadIdx.x - d] : 0;
        __syncthreads();
        sd[threadIdx.x] += t;
        __syncthreads();
    }
    int run = sd[threadIdx.x] - s;   // exclusive prefix for this thread's chunk
    for (int j = 0; j < per; j++) {
        int idx = base + j;
        if (idx < n) {
            off[idx] = run;
            cur[idx] = run;
            run += cnt[idx];
        }
    }
    if (threadIdx.x == 1023) off[n] = sd[1023];
}

// ============================================================================
// K2: scatter packed edge records into u-sorted and p-sorted lists.
// pack: {e|t<<20, other|s<<16|wn<<18|wm<<22, wd0|wd1<<9|wd2<<18, 0}
// ============================================================================
__global__ __launch_bounds__(256) void k_scatter(
    const int* __restrict__ u_idx, const int* __restrict__ p_idx,
    const int* __restrict__ t_idx, const int* __restrict__ s_idx,
    const int* __restrict__ wn_idx, const int* __restrict__ wd_idx,
    const int* __restrict__ wm_idx,
    int* __restrict__ cur_u, int* __restrict__ cur_p,
    int4* __restrict__ upack, int4* __restrict__ ppack)
{
    for (int e = blockIdx.x * 256 + threadIdx.x; e < E_N; e += gridDim.x * 256) {
        int u = u_idx[e], p = p_idx[e], t = t_idx[e];
        int s = s_idx[e], wn = wn_idx[e], wm = wm_idx[e];
        int d0 = wd_idx[e * 3 + 0], d1 = wd_idx[e * 3 + 1], d2 = wd_idx[e * 3 + 2];
        int w0 = e | (t << 20);
        int sp = (s << 16) | (wn << 18) | (wm << 22);
        int dp = d0 | (d1 << 9) | (d2 << 18);
        int pu = atomicAdd(&cur_u[u], 1);
        upack[pu] = make_int4(w0, p | sp, dp, 0);
        int pp = atomicAdd(&cur_p[p], 1);
        ppack[pp] = make_int4(w0, u | sp, dp, 0);
    }
}

// ============================================================================
// K3: segment accumulation — one 64-lane wave per segment (user or poi).
// acc (float2/lane) = sum over edges of other_emb + time_emb + e_W.
// LDS hist of the 7 small/day targets -> u8 count row (no global atomics).
// mode 1 (user): write X row + sumsq (pad rows: X=0, sq=INF). mode 0 (poi):
// write mean directly to out.
// ============================================================================
__global__ __launch_bounds__(256) void k_seg(
    const int4* __restrict__ pack, const int* __restrict__ off,
    const float2* __restrict__ oemb, const float2* __restrict__ temb,
    const float2* __restrict__ ew, unsigned char* __restrict__ Cmat,
    float2* __restrict__ outv, float* __restrict__ sq,
    int nseg, int nreal, int mode)
{
    __shared__ int hist[4][CSTR];
    int wv = threadIdx.x >> 6;
    int lane = threadIdx.x & 63;
    int seg = blockIdx.x * 4 + wv;
    if (seg >= nseg) return;

    if (seg >= nreal) {                       // user-mode pad rows for knn
        outv[(size_t)seg * 64 + lane] = make_float2(0.f, 0.f);
        if (mode == 1 && lane == 0) sq[seg] = INFINITY;
        return;
    }

    int* h = hist[wv];
    for (int i = lane; i < CSTR; i += 64) h[i] = 0;

    int o0 = off[seg], o1 = off[seg + 1];
    float2 acc = make_float2(0.f, 0.f);

    int4 pk = make_int4(0, 0, 0, 0);
    if (o0 < o1) pk = pack[o0];
    for (int i = o0; i < o1; ++i) {
        int4 nx = pk;
        if (i + 1 < o1) nx = pack[i + 1];     // prefetch next record
        int e = pk.x & 0xFFFFF, t = (pk.x >> 20) & 63;
        int oth = pk.y & 0xFFFF;
        int s = (pk.y >> 16) & 3, wn = (pk.y >> 18) & 15, wm = (pk.y >> 22) & 15;
        int q0 = pk.z & 511, q1 = (pk.z >> 9) & 511, q2 = (pk.z >> 18) & 511;

        float2 wf = ew[(size_t)e * 64 + lane];
        float2 ov = oemb[(size_t)oth * 64 + lane];
        float2 tv = temb[t * 64 + lane];
        acc.x += ov.x + tv.x + wf.x;
        acc.y += ov.y + tv.y + wf.y;

        int b = t;
        b = (lane == 1) ? 48 + s : b;
        b = (lane == 2) ? 52 + wn : b;
        b = (lane == 3) ? 62 + wm : b;
        b = (lane == 4) ? 74 + q0 : b;
        b = (lane == 5) ? 74 + q1 : b;
        b = (lane == 6) ? 74 + q2 : b;
        if (lane < 7) atomicAdd(&h[b], 1);
        pk = nx;
    }

    float den = (float)(o1 - o0) + EPSF;
    float2 xm = make_float2(acc.x / den, acc.y / den);
    outv[(size_t)seg * 64 + lane] = xm;

    if (mode == 1) {
        float d = xm.x * xm.x + xm.y * xm.y;
        for (int m = 32; m >= 1; m >>= 1) d += __shfl_xor(d, m);
        if (lane == 0) sq[seg] = d;
    }

    // write u8 count row (480 bytes, coalesced uchar4)
    unsigned char* crow = Cmat + (size_t)seg * CSTR;
    for (int i = lane; i < CSTR / 4; i += 64) {
        uchar4 v;
        v.x = (unsigned char)h[4 * i + 0];
        v.y = (unsigned char)h[4 * i + 1];
        v.z = (unsigned char)h[4 * i + 2];
        v.w = (unsigned char)h[4 * i + 3];
        *(uchar4*)&crow[4 * i] = v;
    }
}

// ============================================================================
// K4: count-GEMM  acc474[d][n] += sum_k C[k][d] * emb[k][n]  (C is u8).
// do_cnt: also accumulate per-column totals (u-side only, counts each edge once)
// ============================================================================
#define DTILE 32
#define KB 16

__global__ __launch_bounds__(256) void k_cgemm(
    const float* __restrict__ emb, const unsigned char* __restrict__ C,
    int K, int kper, float* __restrict__ acc474, float* __restrict__ cnt_all,
    int do_cnt)
{
    __shared__ __align__(16) float se[KB][128];
    __shared__ __align__(16) float scf[KB][DTILE];
    int d0 = blockIdx.x * DTILE;
    int k0 = blockIdx.y * kper;
    int k1 = min(K, k0 + kper);
    int n2 = (threadIdx.x & 63) * 2;
    int dg = threadIdx.x >> 6;
    int dbase = dg * 8;
    bool cntth = do_cnt && ((threadIdx.x & 63) == 0);

    float acc[8][2];
    float ca[8];
#pragma unroll
    for (int j = 0; j < 8; j++) { acc[j][0] = 0.f; acc[j][1] = 0.f; ca[j] = 0.f; }

    for (int kb = k0; kb < k1; kb += KB) {
        __syncthreads();
        for (int t = threadIdx.x; t < KB * 64; t += 256) {
            int kk = t >> 6, cc = (t & 63) * 2;
            float2 v = make_float2(0.f, 0.f);
            if (kb + kk < k1) v = *(const float2*)&emb[(size_t)(kb + kk) * 128 + cc];
            *(float2*)&se[kk][cc] = v;
        }
        for (int t = threadIdx.x; t < KB * DTILE; t += 256) {
            int kk = t >> 5, dd = t & 31;
            scf[kk][dd] = (kb + kk < k1 && d0 + dd < NCOL)
                          ? (float)C[(size_t)(kb + kk) * CSTR + d0 + dd] : 0.f;
        }
        __syncthreads();
#pragma unroll 4
        for (int kk = 0; kk < KB; kk++) {
            float2 e = *(const float2*)&se[kk][n2];
            float4 c0 = *(const float4*)&scf[kk][dbase];
            float4 c1 = *(const float4*)&scf[kk][dbase + 4];
            float cf[8] = { c0.x, c0.y, c0.z, c0.w, c1.x, c1.y, c1.z, c1.w };
#pragma unroll
            for (int j = 0; j < 8; j++) {
                acc[j][0] = fmaf(cf[j], e.x, acc[j][0]);
                acc[j][1] = fmaf(cf[j], e.y, acc[j][1]);
            }
            if (cntth) {
#pragma unroll
                for (int j = 0; j < 8; j++) ca[j] += cf[j];
            }
        }
    }
#pragma unroll
    for (int j = 0; j < 8; j++) {
        int d = d0 + dbase + j;
        if (d < NCOL) {
            unsafeAtomicAdd(&acc474[d * 128 + n2], acc[j][0]);
            unsafeAtomicAdd(&acc474[d * 128 + n2 + 1], acc[j][1]);
        }
    }
    if (cntth) {
#pragma unroll
        for (int j = 0; j < 8; j++) {
            int d = d0 + dbase + j;
            if (d < NCOL) unsafeAtomicAdd(&cnt_all[d], ca[j]);
        }
    }
}

// ============================================================================
// K5: normalize small/day targets and scatter to output regions
// ============================================================================
__global__ __launch_bounds__(256) void k_norm_all(
    const float* __restrict__ acc474, const float* __restrict__ cnt_all,
    float* __restrict__ out)
{
    int idx = blockIdx.x * 256 + threadIdx.x;   // < NCOL*128 = 60672
    int row = idx >> 7, c = idx & 127;
    float v = acc474[idx] / (cnt_all[row] + EPSF);
    int off;
    if (row < 48)      off = O_TIME + row * 128 + c;
    else if (row < 52) off = O_SEA + (row - 48) * 128 + c;
    else if (row < 62) off = O_WEA + (row - 52) * 128 + c;
    else if (row < 74) off = O_MON + (row - 62) * 128 + c;
    else               off = O_DAY + (row - 74) * 128 + c;
    out[off] = v;
}

// ============================================================================
// K6: knn — f32 tiled GEMM (X @ X^T) with fused online top-6 per row.
// (d2,idx) packed in u64 => single compare reproduces top_k tie-breaking.
// ============================================================================
#define KNN_PAD 134

__device__ inline void ins6(unsigned long long (&l)[6], unsigned long long cand) {
    if (cand < l[5]) {
        l[5] = cand;
#pragma unroll
        for (int k = 5; k >= 1; k--) {
            unsigned long long a = l[k - 1], b = l[k];
            l[k - 1] = (b < a) ? b : a;
            l[k] = (b < a) ? a : b;
        }
    }
}

__global__ __launch_bounds__(256) void k_knn(
    const float* __restrict__ X, const float* __restrict__ sq,
    unsigned long long* __restrict__ lists)
{
    __shared__ __align__(16) unsigned char smem[49152];
    float* Ab = (float*)smem;                  // [32][KNN_PAD]
    float* Bb = Ab + 32 * KNN_PAD;
    unsigned long long* mb = (unsigned long long*)smem;  // [128][8][6] reuse

    int rb = blockIdx.x / NCH, ch = blockIdx.x % NCH;
    int row0 = rb * 128;
    int tid = threadIdx.x;
    int tr = tid >> 3;   // 0..31 -> rows tr*4 .. +3
    int tc = tid & 7;    // 0..7  -> cols tc*16 .. +15

    float sqr[4];
#pragma unroll
    for (int i = 0; i < 4; i++) sqr[i] = sq[row0 + tr * 4 + i];

    unsigned long long lst[4][6];
#pragma unroll
    for (int i = 0; i < 4; i++)
#pragma unroll
        for (int k = 0; k < 6; k++) lst[i][k] = ~0ull;

    for (int ct = ch; ct < CT; ct += NCH) {
        int col0 = ct * 128;
        float acc[4][16];
#pragma unroll
        for (int i = 0; i < 4; i++)
#pragma unroll
            for (int j = 0; j < 16; j++) acc[i][j] = 0.f;

        for (int kc = 0; kc < 4; kc++) {
            __syncthreads();
#pragma unroll
            for (int i = 0; i < 16; i++) {
                int lin = i * 256 + tid;
                int r = lin >> 5, kk = lin & 31;
                Ab[kk * KNN_PAD + r] = X[(row0 + r) * 128 + kc * 32 + kk];
                Bb[kk * KNN_PAD + r] = X[(col0 + r) * 128 + kc * 32 + kk];
            }
            __syncthreads();
#pragma unroll 2
            for (int kk = 0; kk < 32; kk++) {
                float a[4], b[16];
                float2 t0 = *(const float2*)&Ab[kk * KNN_PAD + tr * 4];
                float2 t1 = *(const float2*)&Ab[kk * KNN_PAD + tr * 4 + 2];
                a[0] = t0.x; a[1] = t0.y; a[2] = t1.x; a[3] = t1.y;
#pragma unroll
                for (int j = 0; j < 8; j++) {
                    float2 tb = *(const float2*)&Bb[kk * KNN_PAD + tc * 16 + j * 2];
                    b[2 * j] = tb.x; b[2 * j + 1] = tb.y;
                }
#pragma unroll
                for (int i = 0; i < 4; i++)
#pragma unroll
                    for (int j = 0; j < 16; j++)
                        acc[i][j] = fmaf(a[i], b[j], acc[i][j]);
            }
        }
#pragma unroll
        for (int j = 0; j < 16; j++) {
            int col = col0 + tc * 16 + j;
            float sqc = sq[col];
#pragma unroll
            for (int i = 0; i < 4; i++) {
                float d2 = fmaxf(fmaf(-2.f, acc[i][j], sqr[i] + sqc), 0.f);
                unsigned long long cand =
                    ((unsigned long long)__float_as_uint(d2) << 32) | (unsigned)col;
                ins6(lst[i], cand);
            }
        }
    }
    __syncthreads();
#pragma unroll
    for (int i = 0; i < 4; i++)
#pragma unroll
        for (int k = 0; k < 6; k++)
            mb[((tr * 4 + i) * 8 + tc) * 6 + k] = lst[i][k];
    __syncthreads();
    if (tid < 128) {
        unsigned long long outl[6];
#pragma unroll
        for (int k = 0; k < 6; k++) outl[k] = ~0ull;
        for (int t = 0; t < 8; t++)
            for (int k = 0; k < 6; k++)
                ins6(outl, mb[(tid * 8 + t) * 6 + k]);
#pragma unroll
        for (int k = 0; k < 6; k++)
            lists[((size_t)(row0 + tid) * NCH + ch) * 6 + k] = outl[k];
    }
}

// ============================================================================
// K7: merge per-chunk top-6 lists, gather 6 rows of X, mean -> out user region
// ============================================================================
__global__ __launch_bounds__(256) void k_final(
    const unsigned long long* __restrict__ lists,
    const float* __restrict__ X, float* __restrict__ out)
{
    int row = blockIdx.x * 4 + (threadIdx.x >> 6);
    int ln = threadIdx.x & 63;
    unsigned long long l[6];
#pragma unroll
    for (int k = 0; k < 6; k++) l[k] = ~0ull;
    if (ln == 0) {
        for (int t = 0; t < NCH; t++)
            for (int k = 0; k < 6; k++)
                ins6(l, lists[((size_t)row * NCH + t) * 6 + k]);
    }
    float s0 = 0.f, s1 = 0.f;
#pragma unroll
    for (int k = 0; k < 6; k++) {
        int idx = __shfl((int)(unsigned)l[k], 0);
        s0 += X[idx * 128 + ln];
        s1 += X[idx * 128 + 64 + ln];
    }
    out[row * 128 + ln] = s0 * (1.f / 6.f);
    out[row * 128 + 64 + ln] = s1 * (1.f / 6.f);
}

// ============================================================================
extern "C" void kernel_launch(void* const* d_in, const int* in_sizes, int n_in,
                              void* d_out, int out_size, void* d_ws, size_t ws_size,
                              hipStream_t stream) {
    const float* uemb = (const float*)d_in[0];
    const float* pemb = (const float*)d_in[1];
    const float2* temb2 = (const float2*)d_in[2];
    // d_in[3..6]: weather/season/day/month embeddings — unused by reference math
    const float2* ew2 = (const float2*)d_in[7];
    const int* u_idx = (const int*)d_in[8];
    const int* p_idx = (const int*)d_in[9];
    const int* t_idx = (const int*)d_in[10];
    const int* s_idx = (const int*)d_in[11];
    const int* wn_idx = (const int*)d_in[12];
    const int* wd_idx = (const int*)d_in[13];
    const int* wm_idx = (const int*)d_in[14];

    float* out = (float*)d_out;
    float* ws = (float*)d_ws;

    int* cnt_u = (int*)(ws + OFF_CNT_U);
    int* cnt_p = (int*)(ws + OFF_CNT_P);
    int* off_u = (int*)(ws + OFF_OFF_U);
    int* off_p = (int*)(ws + OFF_OFF_P);
    int* cur_u = (int*)(ws + OFF_CUR_U);
    int* cur_p = (int*)(ws + OFF_CUR_P);
    int4* upack = (int4*)(ws + OFF_UPACK);
    int4* ppack = (int4*)(ws + OFF_PPACK);
    unsigned char* Cu = (unsigned char*)(ws + OFF_CU);
    unsigned char* Cp = (unsigned char*)(ws + OFF_CP);
    float* acc474 = ws + OFF_ACC474;
    float* cnt_all = ws + OFF_CNTALL;
    float* X = ws + OFF_X;
    float* sqv = ws + OFF_SQ;
    unsigned long long* lists = (unsigned long long*)(ws + OFF_UPACK); // overlay

    // zero: degree counters + acc474 + cnt_all (everything else fully written)
    hipMemsetAsync(ws, 0, 60000 * sizeof(float), stream);
    hipMemsetAsync(ws + OFF_ACC474, 0, (61440 + 480) * sizeof(float), stream);

    k_hist<<<512, 256, 0, stream>>>(u_idx, p_idx, cnt_u, cnt_p);
    k_scan<<<2, 1024, 0, stream>>>(cnt_u, off_u, cur_u, cnt_p, off_p, cur_p);
    k_scatter<<<1024, 256, 0, stream>>>(u_idx, p_idx, t_idx, s_idx, wn_idx, wd_idx,
                                        wm_idx, cur_u, cur_p, upack, ppack);

    // poi pass first (reads ppack), then user pass
    k_seg<<<12500, 256, 0, stream>>>(ppack, off_p, (const float2*)uemb, temb2, ew2,
                                     Cp, (float2*)(out + O_POI), nullptr,
                                     P_N, P_N, 0);
    k_seg<<<2528, 256, 0, stream>>>(upack, off_u, (const float2*)pemb, temb2, ew2,
                                    Cu, (float2*)X, sqv,
                                    XR, U_N, 1);

    // small/day targets: acc474 = Cu^T @ user_emb + Cp^T @ poi_emb
    k_cgemm<<<dim3(15, 8), 256, 0, stream>>>(uemb, Cu, U_N, 1250, acc474, cnt_all, 1);
    k_cgemm<<<dim3(15, 40), 256, 0, stream>>>(pemb, Cp, P_N, 1250, acc474, cnt_all, 0);
    k_norm_all<<<237, 256, 0, stream>>>(acc474, cnt_all, out);

    k_knn<<<CT * NCH, 256, 0, stream>>>(X, sqv, lists);
    k_final<<<U_N / 4, 256, 0, stream>>>(lists, X, out + O_USER);
}

// Round 6
// 2686.707 us; speedup vs baseline: 2.2225x; 1.0616x over previous
//
#include <hip/hip_runtime.h>
#include <math.h>

#define U_N 10000
#define P_N 50000
#define T_N 48
#define W_N 10
#define S_N 4
#define DW_N 400
#define MW_N 12
#define E_N 1000000
#define XR 10112          // 79*128 padded rows for knn
#define NCH 16            // column chunks for knn grid
#define CT 79             // 10112/128 col tiles
#define EPSF 1e-9f
#define NCOL 474          // 48 time + 4 season + 10 weather + 12 month + 400 day
#define CSTR 480          // padded row stride of count matrices

// ---- workspace offsets (in floats) ----
#define OFF_CNT_U   0
#define OFF_CNT_P   10000
#define OFF_OFF_U   60000        // int[10001]
#define OFF_OFF_P   70016        // int[50001]
#define OFF_CUR_U   120032
#define OFF_CUR_P   130032
#define OFF_UPACK   180032       // int4[1M]   (k_knn lists overlay here later)
#define OFF_PPACK   4180032      // int4[1M]
#define OFF_CU      8180032      // u8[10000*480]
#define OFF_CP      9380032      // u8[50000*480]
#define OFF_ACC474  15380032     // float[480*128]
#define OFF_CNTALL  15441472     // float[480]
#define OFF_X       15441952     // float[10112*128]
#define OFF_SQ      16736288     // float[10112]

// ---- output offsets (floats): user, poi, time, weather, season, day, month ----
#define O_USER 0
#define O_POI  1280000
#define O_TIME 7680000
#define O_WEA  7686144
#define O_SEA  7687424
#define O_DAY  7687936
#define O_MON  7739136

// ============================================================================
// K0: degree histograms
// ============================================================================
__global__ __launch_bounds__(256) void k_hist(
    const int* __restrict__ u_idx, const int* __restrict__ p_idx,
    int* __restrict__ cnt_u, int* __restrict__ cnt_p)
{
    for (int e = blockIdx.x * 256 + threadIdx.x; e < E_N; e += gridDim.x * 256) {
        atomicAdd(&cnt_u[u_idx[e]], 1);
        atomicAdd(&cnt_p[p_idx[e]], 1);
    }
}

// ============================================================================
// K1: exclusive scan (block 0: users, block 1: pois) -> off[n+1], cur copy
// ============================================================================
__global__ __launch_bounds__(1024) void k_scan(
    const int* __restrict__ cnt_u, int* __restrict__ off_u, int* __restrict__ cur_u,
    const int* __restrict__ cnt_p, int* __restrict__ off_p, int* __restrict__ cur_p)
{
    const int n = (blockIdx.x == 0) ? U_N : P_N;
    const int* cnt = (blockIdx.x == 0) ? cnt_u : cnt_p;
    int* off = (blockIdx.x == 0) ? off_u : off_p;
    int* cur = (blockIdx.x == 0) ? cur_u : cur_p;
    __shared__ int sd[1024];
    int per = (n + 1023) >> 10;
    int base = threadIdx.x * per;
    int s = 0;
    for (int j = 0; j < per; j++) {
        int idx = base + j;
        if (idx < n) s += cnt[idx];
    }
    sd[threadIdx.x] = s;
    __syncthreads();
    for (int d = 1; d < 1024; d <<= 1) {
        int t = (threadIdx.x >= d) ? sd[threadIdx.x - d] : 0;
        __syncthreads();
        sd[threadIdx.x] += t;
        __syncthreads();
    }
    int run = sd[threadIdx.x] - s;
    for (int j = 0; j < per; j++) {
        int idx = base + j;
        if (idx < n) {
            off[idx] = run;
            cur[idx] = run;
            run += cnt[idx];
        }
    }
    if (threadIdx.x == 1023) off[n] = sd[1023];
}

// ============================================================================
// K2: scatter packed edge records into u-sorted and p-sorted lists.
// ============================================================================
__global__ __launch_bounds__(256) void k_scatter(
    const int* __restrict__ u_idx, const int* __restrict__ p_idx,
    const int* __restrict__ t_idx, const int* __restrict__ s_idx,
    const int* __restrict__ wn_idx, const int* __restrict__ wd_idx,
    const int* __restrict__ wm_idx,
    int* __restrict__ cur_u, int* __restrict__ cur_p,
    int4* __restrict__ upack, int4* __restrict__ ppack)
{
    for (int e = blockIdx.x * 256 + threadIdx.x; e < E_N; e += gridDim.x * 256) {
        int u = u_idx[e], p = p_idx[e], t = t_idx[e];
        int s = s_idx[e], wn = wn_idx[e], wm = wm_idx[e];
        int d0 = wd_idx[e * 3 + 0], d1 = wd_idx[e * 3 + 1], d2 = wd_idx[e * 3 + 2];
        int w0 = e | (t << 20);
        int sp = (s << 16) | (wn << 18) | (wm << 22);
        int dp = d0 | (d1 << 9) | (d2 << 18);
        int pu = atomicAdd(&cur_u[u], 1);
        upack[pu] = make_int4(w0, p | sp, dp, 0);
        int pp = atomicAdd(&cur_p[p], 1);
        ppack[pp] = make_int4(w0, u | sp, dp, 0);
    }
}

// ============================================================================
// K3: segment accumulation — one 64-lane wave per segment (user or poi).
// ============================================================================
__global__ __launch_bounds__(256) void k_seg(
    const int4* __restrict__ pack, const int* __restrict__ off,
    const float2* __restrict__ oemb, const float2* __restrict__ temb,
    const float2* __restrict__ ew, unsigned char* __restrict__ Cmat,
    float2* __restrict__ outv, float* __restrict__ sq,
    int nseg, int nreal, int mode)
{
    __shared__ int hist[4][CSTR];
    int wv = threadIdx.x >> 6;
    int lane = threadIdx.x & 63;
    int seg = blockIdx.x * 4 + wv;
    if (seg >= nseg) return;

    if (seg >= nreal) {                       // user-mode pad rows for knn
        outv[(size_t)seg * 64 + lane] = make_float2(0.f, 0.f);
        if (mode == 1 && lane == 0) sq[seg] = INFINITY;
        return;
    }

    int* h = hist[wv];
    for (int i = lane; i < CSTR; i += 64) h[i] = 0;

    int o0 = off[seg], o1 = off[seg + 1];
    float2 acc = make_float2(0.f, 0.f);

    int4 pk = make_int4(0, 0, 0, 0);
    if (o0 < o1) pk = pack[o0];
    for (int i = o0; i < o1; ++i) {
        int4 nx = pk;
        if (i + 1 < o1) nx = pack[i + 1];
        int e = pk.x & 0xFFFFF, t = (pk.x >> 20) & 63;
        int oth = pk.y & 0xFFFF;
        int s = (pk.y >> 16) & 3, wn = (pk.y >> 18) & 15, wm = (pk.y >> 22) & 15;
        int q0 = pk.z & 511, q1 = (pk.z >> 9) & 511, q2 = (pk.z >> 18) & 511;

        float2 wf = ew[(size_t)e * 64 + lane];
        float2 ov = oemb[(size_t)oth * 64 + lane];
        float2 tv = temb[t * 64 + lane];
        acc.x += ov.x + tv.x + wf.x;
        acc.y += ov.y + tv.y + wf.y;

        int b = t;
        b = (lane == 1) ? 48 + s : b;
        b = (lane == 2) ? 52 + wn : b;
        b = (lane == 3) ? 62 + wm : b;
        b = (lane == 4) ? 74 + q0 : b;
        b = (lane == 5) ? 74 + q1 : b;
        b = (lane == 6) ? 74 + q2 : b;
        if (lane < 7) atomicAdd(&h[b], 1);
        pk = nx;
    }

    float den = (float)(o1 - o0) + EPSF;
    float2 xm = make_float2(acc.x / den, acc.y / den);
    outv[(size_t)seg * 64 + lane] = xm;

    if (mode == 1) {
        float d = xm.x * xm.x + xm.y * xm.y;
        for (int m = 32; m >= 1; m >>= 1) d += __shfl_xor(d, m);
        if (lane == 0) sq[seg] = d;
    }

    unsigned char* crow = Cmat + (size_t)seg * CSTR;
    for (int i = lane; i < CSTR / 4; i += 64) {
        uchar4 v;
        v.x = (unsigned char)h[4 * i + 0];
        v.y = (unsigned char)h[4 * i + 1];
        v.z = (unsigned char)h[4 * i + 2];
        v.w = (unsigned char)h[4 * i + 3];
        *(uchar4*)&crow[4 * i] = v;
    }
}

// ============================================================================
// K4: count-GEMM  acc474[d][n] += sum_k C[k][d] * emb[k][n]  (C is u8).
// DTILE=64: halves redundant emb traffic vs 32.
// ============================================================================
#define DTILE 64
#define KB 16

__global__ __launch_bounds__(256) void k_cgemm(
    const float* __restrict__ emb, const unsigned char* __restrict__ C,
    int K, int kper, float* __restrict__ acc474, float* __restrict__ cnt_all,
    int do_cnt)
{
    __shared__ __align__(16) float se[KB][128];
    __shared__ __align__(16) float scf[KB][DTILE];
    int d0 = blockIdx.x * DTILE;
    int k0 = blockIdx.y * kper;
    int k1 = min(K, k0 + kper);
    int n2 = (threadIdx.x & 63) * 2;
    int dg = threadIdx.x >> 6;      // 0..3 (wave-uniform)
    int dbase = dg * 16;
    bool cntth = do_cnt && ((threadIdx.x & 63) == 0);

    float acc[16][2];
    float ca[16];
#pragma unroll
    for (int j = 0; j < 16; j++) { acc[j][0] = 0.f; acc[j][1] = 0.f; ca[j] = 0.f; }

    for (int kb = k0; kb < k1; kb += KB) {
        __syncthreads();
        for (int t = threadIdx.x; t < KB * 64; t += 256) {
            int kk = t >> 6, cc = (t & 63) * 2;
            float2 v = make_float2(0.f, 0.f);
            if (kb + kk < k1) v = *(const float2*)&emb[(size_t)(kb + kk) * 128 + cc];
            *(float2*)&se[kk][cc] = v;
        }
        for (int t = threadIdx.x; t < KB * DTILE; t += 256) {
            int kk = t >> 6, dd = t & 63;
            scf[kk][dd] = (kb + kk < k1 && d0 + dd < NCOL)
                          ? (float)C[(size_t)(kb + kk) * CSTR + d0 + dd] : 0.f;
        }
        __syncthreads();
#pragma unroll 4
        for (int kk = 0; kk < KB; kk++) {
            float2 e = *(const float2*)&se[kk][n2];
            float cf[16];
#pragma unroll
            for (int q = 0; q < 4; q++) {
                float4 c = *(const float4*)&scf[kk][dbase + q * 4];
                cf[q * 4 + 0] = c.x; cf[q * 4 + 1] = c.y;
                cf[q * 4 + 2] = c.z; cf[q * 4 + 3] = c.w;
            }
#pragma unroll
            for (int j = 0; j < 16; j++) {
                acc[j][0] = fmaf(cf[j], e.x, acc[j][0]);
                acc[j][1] = fmaf(cf[j], e.y, acc[j][1]);
            }
            if (cntth) {
#pragma unroll
                for (int j = 0; j < 16; j++) ca[j] += cf[j];
            }
        }
    }
#pragma unroll
    for (int j = 0; j < 16; j++) {
        int d = d0 + dbase + j;
        if (d < NCOL) {
            unsafeAtomicAdd(&acc474[d * 128 + n2], acc[j][0]);
            unsafeAtomicAdd(&acc474[d * 128 + n2 + 1], acc[j][1]);
        }
    }
    if (cntth) {
#pragma unroll
        for (int j = 0; j < 16; j++) {
            int d = d0 + dbase + j;
            if (d < NCOL) unsafeAtomicAdd(&cnt_all[d], ca[j]);
        }
    }
}

// ============================================================================
// K5: normalize small/day targets and scatter to output regions
// ============================================================================
__global__ __launch_bounds__(256) void k_norm_all(
    const float* __restrict__ acc474, const float* __restrict__ cnt_all,
    float* __restrict__ out)
{
    int idx = blockIdx.x * 256 + threadIdx.x;   // < NCOL*128 = 60672
    int row = idx >> 7, c = idx & 127;
    float v = acc474[idx] / (cnt_all[row] + EPSF);
    int off;
    if (row < 48)      off = O_TIME + row * 128 + c;
    else if (row < 52) off = O_SEA + (row - 48) * 128 + c;
    else if (row < 62) off = O_WEA + (row - 52) * 128 + c;
    else if (row < 74) off = O_MON + (row - 62) * 128 + c;
    else               off = O_DAY + (row - 74) * 128 + c;
    out[off] = v;
}

// ============================================================================
// K6: knn — f32 tiled GEMM (X @ X^T) with fused online top-6 per row.
// Conflict-free LDS: thread tc owns cols {tc*2 + 16j}, so B-reads hit banks
// {0,2,..,14}+const (broadcast within tc-groups). Merge across the 8 threads
// of a row via wave shuffles (no LDS merge buffer) -> 34KB LDS, 4 blocks/CU.
// ============================================================================
#define KNN_PAD 134

__device__ inline void ins6(unsigned long long (&l)[6], unsigned long long cand) {
    if (cand < l[5]) {
        l[5] = cand;
#pragma unroll
        for (int k = 5; k >= 1; k--) {
            unsigned long long a = l[k - 1], b = l[k];
            l[k - 1] = (b < a) ? b : a;
            l[k] = (b < a) ? a : b;
        }
    }
}

__global__ __launch_bounds__(256) void k_knn(
    const float* __restrict__ X, const float* __restrict__ sq,
    unsigned long long* __restrict__ lists)
{
    __shared__ __align__(16) float Ab[32 * KNN_PAD];
    __shared__ __align__(16) float Bb[32 * KNN_PAD];

    int rb = blockIdx.x / NCH, ch = blockIdx.x % NCH;
    int row0 = rb * 128;
    int tid = threadIdx.x;
    int tr = tid >> 3;   // 0..31 -> rows tr*4 .. +3
    int tc = tid & 7;    // 0..7  -> cols {tc*2 + 16j, +1}

    float sqr[4];
#pragma unroll
    for (int i = 0; i < 4; i++) sqr[i] = sq[row0 + tr * 4 + i];

    unsigned long long lst[4][6];
#pragma unroll
    for (int i = 0; i < 4; i++)
#pragma unroll
        for (int k = 0; k < 6; k++) lst[i][k] = ~0ull;

    for (int ct = ch; ct < CT; ct += NCH) {
        int col0 = ct * 128;
        float acc[4][16];
#pragma unroll
        for (int i = 0; i < 4; i++)
#pragma unroll
            for (int j = 0; j < 16; j++) acc[i][j] = 0.f;

        for (int kc = 0; kc < 4; kc++) {
            __syncthreads();
#pragma unroll
            for (int i = 0; i < 16; i++) {
                int lin = i * 256 + tid;
                int r = lin >> 5, kk = lin & 31;
                Ab[kk * KNN_PAD + r] = X[(row0 + r) * 128 + kc * 32 + kk];
                Bb[kk * KNN_PAD + r] = X[(col0 + r) * 128 + kc * 32 + kk];
            }
            __syncthreads();
#pragma unroll 2
            for (int kk = 0; kk < 32; kk++) {
                float a[4], b[16];
                float2 t0 = *(const float2*)&Ab[kk * KNN_PAD + tr * 4];
                float2 t1 = *(const float2*)&Ab[kk * KNN_PAD + tr * 4 + 2];
                a[0] = t0.x; a[1] = t0.y; a[2] = t1.x; a[3] = t1.y;
#pragma unroll
                for (int j = 0; j < 8; j++) {
                    float2 tb = *(const float2*)&Bb[kk * KNN_PAD + tc * 2 + j * 16];
                    b[2 * j] = tb.x; b[2 * j + 1] = tb.y;
                }
#pragma unroll
                for (int i = 0; i < 4; i++)
#pragma unroll
                    for (int j = 0; j < 16; j++)
                        acc[i][j] = fmaf(a[i], b[j], acc[i][j]);
            }
        }
#pragma unroll
        for (int j = 0; j < 8; j++) {
            int c0 = col0 + tc * 2 + j * 16;
            float sq0 = sq[c0], sq1 = sq[c0 + 1];
#pragma unroll
            for (int i = 0; i < 4; i++) {
                float d20 = fmaxf(fmaf(-2.f, acc[i][2 * j], sqr[i] + sq0), 0.f);
                float d21 = fmaxf(fmaf(-2.f, acc[i][2 * j + 1], sqr[i] + sq1), 0.f);
                ins6(lst[i], ((unsigned long long)__float_as_uint(d20) << 32) | (unsigned)c0);
                ins6(lst[i], ((unsigned long long)__float_as_uint(d21) << 32) | (unsigned)(c0 + 1));
            }
        }
    }

    // merge the 8 per-thread lists of each row via wave butterfly (lanes tr*8+tc)
#pragma unroll
    for (int m = 1; m <= 4; m <<= 1) {
#pragma unroll
        for (int i = 0; i < 4; i++) {
            unsigned long long tmp[6];
#pragma unroll
            for (int k = 0; k < 6; k++) tmp[k] = lst[i][k];
#pragma unroll
            for (int k = 0; k < 6; k++) {
                unsigned lo = (unsigned)(tmp[k] & 0xffffffffull);
                unsigned hi = (unsigned)(tmp[k] >> 32);
                lo = (unsigned)__shfl_xor((int)lo, m);
                hi = (unsigned)__shfl_xor((int)hi, m);
                ins6(lst[i], ((unsigned long long)hi << 32) | lo);
            }
        }
    }
    if (tc == 0) {
#pragma unroll
        for (int i = 0; i < 4; i++)
#pragma unroll
            for (int k = 0; k < 6; k++)
                lists[((size_t)(row0 + tr * 4 + i) * NCH + ch) * 6 + k] = lst[i][k];
    }
}

// ============================================================================
// K7: merge per-chunk top-6 lists, gather 6 rows of X, mean -> out user region
// ============================================================================
__global__ __launch_bounds__(256) void k_final(
    const unsigned long long* __restrict__ lists,
    const float* __restrict__ X, float* __restrict__ out)
{
    int row = blockIdx.x * 4 + (threadIdx.x >> 6);
    int ln = threadIdx.x & 63;
    unsigned long long l[6];
#pragma unroll
    for (int k = 0; k < 6; k++) l[k] = ~0ull;
    if (ln == 0) {
        for (int t = 0; t < NCH; t++)
            for (int k = 0; k < 6; k++)
                ins6(l, lists[((size_t)row * NCH + t) * 6 + k]);
    }
    float s0 = 0.f, s1 = 0.f;
#pragma unroll
    for (int k = 0; k < 6; k++) {
        int idx = __shfl((int)(unsigned)l[k], 0);
        s0 += X[idx * 128 + ln];
        s1 += X[idx * 128 + 64 + ln];
    }
    out[row * 128 + ln] = s0 * (1.f / 6.f);
    out[row * 128 + 64 + ln] = s1 * (1.f / 6.f);
}

// ============================================================================
extern "C" void kernel_launch(void* const* d_in, const int* in_sizes, int n_in,
                              void* d_out, int out_size, void* d_ws, size_t ws_size,
                              hipStream_t stream) {
    const float* uemb = (const float*)d_in[0];
    const float* pemb = (const float*)d_in[1];
    const float2* temb2 = (const float2*)d_in[2];
    const float2* ew2 = (const float2*)d_in[7];
    const int* u_idx = (const int*)d_in[8];
    const int* p_idx = (const int*)d_in[9];
    const int* t_idx = (const int*)d_in[10];
    const int* s_idx = (const int*)d_in[11];
    const int* wn_idx = (const int*)d_in[12];
    const int* wd_idx = (const int*)d_in[13];
    const int* wm_idx = (const int*)d_in[14];

    float* out = (float*)d_out;
    float* ws = (float*)d_ws;

    int* cnt_u = (int*)(ws + OFF_CNT_U);
    int* cnt_p = (int*)(ws + OFF_CNT_P);
    int* off_u = (int*)(ws + OFF_OFF_U);
    int* off_p = (int*)(ws + OFF_OFF_P);
    int* cur_u = (int*)(ws + OFF_CUR_U);
    int* cur_p = (int*)(ws + OFF_CUR_P);
    int4* upack = (int4*)(ws + OFF_UPACK);
    int4* ppack = (int4*)(ws + OFF_PPACK);
    unsigned char* Cu = (unsigned char*)(ws + OFF_CU);
    unsigned char* Cp = (unsigned char*)(ws + OFF_CP);
    float* acc474 = ws + OFF_ACC474;
    float* cnt_all = ws + OFF_CNTALL;
    float* X = ws + OFF_X;
    float* sqv = ws + OFF_SQ;
    unsigned long long* lists = (unsigned long long*)(ws + OFF_UPACK); // overlay

    hipMemsetAsync(ws, 0, 60000 * sizeof(float), stream);
    hipMemsetAsync(ws + OFF_ACC474, 0, (61440 + 480) * sizeof(float), stream);

    k_hist<<<512, 256, 0, stream>>>(u_idx, p_idx, cnt_u, cnt_p);
    k_scan<<<2, 1024, 0, stream>>>(cnt_u, off_u, cur_u, cnt_p, off_p, cur_p);
    k_scatter<<<1024, 256, 0, stream>>>(u_idx, p_idx, t_idx, s_idx, wn_idx, wd_idx,
                                        wm_idx, cur_u, cur_p, upack, ppack);

    k_seg<<<12500, 256, 0, stream>>>(ppack, off_p, (const float2*)uemb, temb2, ew2,
                                     Cp, (float2*)(out + O_POI), nullptr,
                                     P_N, P_N, 0);
    k_seg<<<2528, 256, 0, stream>>>(upack, off_u, (const float2*)pemb, temb2, ew2,
                                    Cu, (float2*)X, sqv,
                                    XR, U_N, 1);

    k_cgemm<<<dim3(8, 8), 256, 0, stream>>>(uemb, Cu, U_N, 1250, acc474, cnt_all, 1);
    k_cgemm<<<dim3(8, 40), 256, 0, stream>>>(pemb, Cp, P_N, 1250, acc474, cnt_all, 0);
    k_norm_all<<<237, 256, 0, stream>>>(acc474, cnt_all, out);

    k_knn<<<CT * NCH, 256, 0, stream>>>(X, sqv, lists);
    k_final<<<U_N / 4, 256, 0, stream>>>(lists, X, out + O_USER);
}